// Round 2
// baseline (2940.478 us; speedup 1.0000x reference)
//
#include <hip/hip_runtime.h>

typedef unsigned short u16;
using short8   = __attribute__((ext_vector_type(8))) short;
using floatx4  = __attribute__((ext_vector_type(4))) float;
using ushortx4 = __attribute__((ext_vector_type(4))) unsigned short;

// window one-sided sizes per layer (WINDOWS/2)
static const int g_halves[12] = {16,16,32,32,64,64,128,128,256,256,256,256};

__device__ __forceinline__ float bf2f(u16 u) {
  union { unsigned int i; float f; } x; x.i = ((unsigned int)u) << 16; return x.f;
}
__device__ __forceinline__ u16 f2bf(float f) {
  union { float f; unsigned int i; } x; x.f = f;
  unsigned int r = x.i + 0x7FFFu + ((x.i >> 16) & 1u);
  return (u16)(r >> 16);
}

// async 16B/lane global->LDS; dest is wave-uniform base, lane l lands at base + l*16
__device__ __forceinline__ void gld_lds16(const u16* g, u16* l) {
  __builtin_amdgcn_global_load_lds(
      (const __attribute__((address_space(1))) unsigned int*)g,
      (__attribute__((address_space(3))) unsigned int*)l, 16, 0, 0);
}

// ---------------------------------------------------------------------------
// fused transpose + f32->bf16 convert: in f32 [z][R][C] -> out bf16 [z][C][R]
// ---------------------------------------------------------------------------
__global__ __launch_bounds__(256) void transpose_cvt(
    const float* __restrict__ in, u16* __restrict__ out, int R, int C,
    size_t inZ, size_t outZ)
{
  __shared__ u16 t[32][33];
  const int tx = threadIdx.x & 31, ty = threadIdx.x >> 5; // 32 x 8
  const size_t bi = (size_t)blockIdx.z * inZ;
  const size_t bo = (size_t)blockIdx.z * outZ;
  const int r0 = blockIdx.y * 32, c0 = blockIdx.x * 32;
#pragma unroll
  for (int j = 0; j < 32; j += 8)
    t[ty + j][tx] = f2bf(in[bi + (size_t)(r0 + ty + j) * C + (c0 + tx)]);
  __syncthreads();
#pragma unroll
  for (int j = 0; j < 32; j += 8)
    out[bo + (size_t)(c0 + ty + j) * R + (r0 + tx)] = t[tx][ty + j];
}

// ---------------------------------------------------------------------------
// GEMM: C[M,N] = A[M,K](bf16) @ B[K,N] given as Bt[N,K](bf16)
// EPI 2: outB = bf16(gelu_exact(acc+bias))
// EPI 3: QKV fused: N=2304; seg0=Q*0.125 -> qg [B,H,S,64]; seg1=K -> kg
//        [B,H,S,64]; seg2=V -> vt [B,H,64,S] (transposed, packed 8B stores)
// EPI 4: split-K partial: outF[(z*M+row)*N+col] = acc
// ---------------------------------------------------------------------------
template<int EPI>
__global__ __launch_bounds__(256) void gemm_bt(
    const u16* __restrict__ A, const u16* __restrict__ Bt,
    const float* __restrict__ biasA, const float* __restrict__ biasB, const float* __restrict__ biasC,
    float* __restrict__ outF, u16* __restrict__ outB,
    u16* __restrict__ qg, u16* __restrict__ kg, u16* __restrict__ vt,
    int M, int N, int K, int KC)
{
  __shared__ __align__(16) u16 lsA[128 * 32];
  __shared__ __align__(16) u16 lsB[128 * 32];
  const int tid  = threadIdx.x;
  const int wave = tid >> 6, lane = tid & 63;
  const int quad = lane >> 4, l16 = lane & 15;
  const int m0 = blockIdx.y * 128, n0 = blockIdx.x * 128;
  const int kz = blockIdx.z * KC;
  const int wm = (wave >> 1) * 64, wn = (wave & 1) * 64;
  const int srow = lane >> 2;          // row within 16-row chunk
  const int skof = (lane & 3) * 8;     // bf16 offset along k

  floatx4 acc[4][4] = {};

  for (int k0 = kz; k0 < kz + KC; k0 += 32) {
    __syncthreads();
#pragma unroll
    for (int c = wave; c < 16; c += 4) {
      if (c < 8)
        gld_lds16(A  + (size_t)(m0 + c * 16 + srow) * K + k0 + skof, lsA + c * 512);
      else
        gld_lds16(Bt + (size_t)(n0 + (c - 8) * 16 + srow) * K + k0 + skof, lsB + (c - 8) * 512);
    }
    __syncthreads();
    short8 af[4], bfr[4];
#pragma unroll
    for (int i = 0; i < 4; ++i)
      af[i]  = *(const short8*)(lsA + (wm + i * 16 + l16) * 32 + quad * 8);
#pragma unroll
    for (int j = 0; j < 4; ++j)
      bfr[j] = *(const short8*)(lsB + (wn + j * 16 + l16) * 32 + quad * 8);
#pragma unroll
    for (int i = 0; i < 4; ++i)
#pragma unroll
      for (int j = 0; j < 4; ++j)
        acc[i][j] = __builtin_amdgcn_mfma_f32_16x16x32_bf16(af[i], bfr[j], acc[i][j], 0, 0, 0);
  }

#pragma unroll
  for (int i = 0; i < 4; ++i)
#pragma unroll
    for (int j = 0; j < 4; ++j) {
      const int col = n0 + wn + j * 16 + l16;
      if (EPI == 3) {
        const int seg = (col >= 1536) ? 2 : (col >= 768) ? 1 : 0;
        const int cc = col - seg * 768;
        const int hh = cc >> 6, dd = cc & 63;
        const float bvl = (seg == 0) ? biasA[cc] : (seg == 1) ? biasB[cc] : biasC[cc];
        const int row0 = m0 + wm + i * 16 + quad * 4;
        const int bI = row0 >> 11, ss = row0 & 2047;
        const int bh = bI * 12 + hh;
        if (seg == 2) {
          ushortx4 pk;
#pragma unroll
          for (int r = 0; r < 4; ++r) pk[r] = f2bf(acc[i][j][r] + bvl);
          *(ushortx4*)(vt + ((size_t)bh * 64 + dd) * 2048 + ss) = pk;
        } else {
          u16* dst = (seg == 0) ? qg : kg;
          const float scl = (seg == 0) ? 0.125f : 1.0f;
#pragma unroll
          for (int r = 0; r < 4; ++r)
            dst[((size_t)bh * 2048 + ss + r) * 64 + dd] = f2bf((acc[i][j][r] + bvl) * scl);
        }
      } else if (EPI == 2) {
        const float bvl = biasA[col];
#pragma unroll
        for (int r = 0; r < 4; ++r) {
          const int row = m0 + wm + i * 16 + quad * 4 + r;
          const size_t idx = (size_t)row * N + col;
          float v = acc[i][j][r] + bvl;
          v = 0.5f * v * (1.0f + erff(v * 0.70710678118654752f));
          outB[idx] = f2bf(v);
        }
      } else { // EPI == 4
#pragma unroll
        for (int r = 0; r < 4; ++r) {
          const int row = m0 + wm + i * 16 + quad * 4 + r;
          outF[((size_t)blockIdx.z * M + row) * N + col] = acc[i][j][r];
        }
      }
    }
}

// ---------------------------------------------------------------------------
// 256x256 8-phase GEMM (HK-derived schedule: T2 swizzle + T3/T4 counted vmcnt
// + T5 setprio). 512 thr = 8 waves (2M x 4N), per-wave out 128x64, BK=64,
// LDS 128 KiB (2 dbuf x {A,B} x 2 halves x 128x64 bf16).
//
// Staging: per phase one half-tile = 2 global_load_lds/thread.  LDS swizzle
// (16B chunk index ^= row&7) realized by pre-swizzling the GLOBAL source
// address (linear LDS dest, rule #21); ds_read applies the same XOR.
// Schedule per K-tile t (buffer cur=t&1):
//   ph0: read A-frags i0-3 + B-frags j0-1; stage A0(t+1)->cur^1; bar; 16 MFMA; bar
//   ph1: read B-frags j2-3;                stage A1(t+1)->cur^1; bar; 16 MFMA; bar
//   ph2: read A-frags i4-7;                stage B0(t+2)->cur;   bar; 16 MFMA; bar
//   ph3:                                   stage B1(t+2)->cur;   bar; 16 MFMA;
//        s_waitcnt vmcnt(4); bar    // all 4 halves of tile t+1 complete;
//                                   // the 4 left in flight are B0/B1(t+2)
// Slot-safety: every LDS slot is overwritten >=1 full barrier phase after its
// last read (B halves of buffer cur are fully consumed by end of ph1; A halves
// of cur^1 were last read in tile t-1's ph2).  Collective availability: each
// wave's vmcnt guards its OWN 2 loads/half; the barrier after the vmcnt makes
// the guarantee collective across all 8 waves.
// EPI 2: bf16(gelu(acc+bias));  EPI 4: f32 split-K partial.
// ---------------------------------------------------------------------------
template<int EPI>
__global__ __launch_bounds__(512, 2) void gemm8p(
    const u16* __restrict__ A, const u16* __restrict__ Bt,
    const float* __restrict__ bias,
    float* __restrict__ outF, u16* __restrict__ outB,
    int M, int N, int K, int KC)
{
  __shared__ __align__(16) u16 ls[2][2][2][8192];   // [buf][op A/B][half][128*64]
  const int tid  = threadIdx.x;
  const int wave = tid >> 6, lane = tid & 63;
  const int quad = lane >> 4, l16 = lane & 15;
  const int lr   = l16 & 7;
  const int m0 = blockIdx.y * 256, n0 = blockIdx.x * 256;
  const int kz = blockIdx.z * KC;
  const int NT = KC >> 6;

  const int ha  = wave >> 2;         // this wave's A half
  const int hbw = (wave >> 1) & 1;   // this wave's B half
  const int cb  = (wave & 1) * 64;   // col base within B half
  const int wm  = (wave >> 2) * 128; // output row base
  const int wn  = (wave & 3) * 64;   // output col base

  // staging geometry: global 16B-chunk g = (ii*8+wave)*64+lane; row=g>>3;
  // source k-chunk = (g&7) ^ (row&7)  (inverse swizzle at the source)
  int srow[2], soff[2];
#pragma unroll
  for (int ii = 0; ii < 2; ++ii) {
    const int g = (ii * 8 + wave) * 64 + lane;
    srow[ii] = g >> 3;
    soff[ii] = ((g & 7) ^ (srow[ii] & 7)) * 8;
  }
  // ds_read swizzled chunk offset for ks=0/1: chunk (ks*4+quad) ^ (row&7)
  int cs[2];
#pragma unroll
  for (int ks = 0; ks < 2; ++ks) cs[ks] = (((ks << 2) | quad) ^ lr) * 8;

  floatx4 acc[8][4] = {};
  short8 af[4][2];   // current i-group (4 m-frags x 2 k-slices)
  short8 bf[4][2];   // all 4 n-frags x 2 k-slices (held across the tile)

#define STG(buf, op, half, base, rb, kc) do { \
  _Pragma("unroll") \
  for (int ii = 0; ii < 2; ++ii) \
    gld_lds16((base) + (size_t)((rb) + (half) * 128 + srow[ii]) * K + (kc) + soff[ii], \
              &ls[buf][op][half][(ii * 8 + wave) * 512]); \
} while (0)

#define RDA(ig) do { \
  _Pragma("unroll") \
  for (int ii = 0; ii < 4; ++ii) \
  _Pragma("unroll") \
  for (int ks = 0; ks < 2; ++ks) \
    af[ii][ks] = *(const short8*)&ls[cur][0][ha][(((ig) * 4 + ii) * 16 + l16) * 64 + cs[ks]]; \
} while (0)

#define RDB(jg) do { \
  _Pragma("unroll") \
  for (int jj = 0; jj < 2; ++jj) \
  _Pragma("unroll") \
  for (int ks = 0; ks < 2; ++ks) \
    bf[(jg) * 2 + jj][ks] = *(const short8*)&ls[cur][1][hbw][(cb + ((jg) * 2 + jj) * 16 + l16) * 64 + cs[ks]]; \
} while (0)

#define MM(ILO, JLO) do { \
  __builtin_amdgcn_s_setprio(1); \
  _Pragma("unroll") \
  for (int ii = 0; ii < 4; ++ii) \
  _Pragma("unroll") \
  for (int jj = 0; jj < 2; ++jj) \
  _Pragma("unroll") \
  for (int ks = 0; ks < 2; ++ks) \
    acc[(ILO) + ii][(JLO) + jj] = __builtin_amdgcn_mfma_f32_16x16x32_bf16( \
        af[ii][ks], bf[(JLO) + jj][ks], acc[(ILO) + ii][(JLO) + jj], 0, 0, 0); \
  __builtin_amdgcn_s_setprio(0); \
} while (0)

  // prologue issue order (FIFO matters for the vmcnt accounting):
  // B0(0),B1(0),A0(0),A1(0),B0(1),B1(1) -> tile0's 4 halves are the oldest 8
  STG(0, 1, 0, Bt, n0, kz); STG(0, 1, 1, Bt, n0, kz);
  STG(0, 0, 0, A,  m0, kz); STG(0, 0, 1, A,  m0, kz);
  STG(1, 1, 0, Bt, n0, kz + 64); STG(1, 1, 1, Bt, n0, kz + 64);
  asm volatile("s_waitcnt vmcnt(4)" ::: "memory");
  __builtin_amdgcn_s_barrier();

  int cur = 0;
  for (int t = 0; t < NT; ++t, cur ^= 1) {
    const int k1 = kz + (t + 1) * 64;
    const int k2 = k1 + 64;
    const bool s1 = (t + 1 < NT), s2 = (t + 2 < NT);
    // phase 0
    RDA(0); RDB(0);
    if (s1) STG(cur ^ 1, 0, 0, A, m0, k1);
    __builtin_amdgcn_s_barrier();
    MM(0, 0);
    __builtin_amdgcn_s_barrier();
    // phase 1
    RDB(1);
    if (s1) STG(cur ^ 1, 0, 1, A, m0, k1);
    __builtin_amdgcn_s_barrier();
    MM(0, 2);
    __builtin_amdgcn_s_barrier();
    // phase 2
    RDA(1);
    if (s2) STG(cur, 1, 0, Bt, n0, k2);
    __builtin_amdgcn_s_barrier();
    MM(4, 2);
    __builtin_amdgcn_s_barrier();
    // phase 3
    if (s2) STG(cur, 1, 1, Bt, n0, k2);
    __builtin_amdgcn_s_barrier();
    MM(4, 0);
    if (s2) asm volatile("s_waitcnt vmcnt(4)" ::: "memory");
    else    asm volatile("s_waitcnt vmcnt(0)" ::: "memory");
    __builtin_amdgcn_s_barrier();
  }
#undef STG
#undef RDA
#undef RDB
#undef MM

#pragma unroll
  for (int i = 0; i < 8; ++i)
#pragma unroll
    for (int j = 0; j < 4; ++j) {
      const int col  = n0 + wn + j * 16 + l16;
      const int row0 = m0 + wm + i * 16 + quad * 4;
      if (EPI == 2) {
        const float bvl = bias[col];
#pragma unroll
        for (int r = 0; r < 4; ++r) {
          float v = acc[i][j][r] + bvl;
          v = 0.5f * v * (1.0f + erff(v * 0.70710678118654752f));
          outB[(size_t)(row0 + r) * N + col] = f2bf(v);
        }
      } else { // EPI == 4
#pragma unroll
        for (int r = 0; r < 4; ++r)
          outF[((size_t)blockIdx.z * M + row0 + r) * N + col] = acc[i][j][r];
      }
    }
}

// ---------------------------------------------------------------------------
// MFMA banded flash attention, barrier-free. grid (S/64, H, B), 256 thr =
// 4 independent waves x 16 queries. K/Q/VT fragments load directly from
// global (coalesced 16B/lane, L2-served); only P round-trips per-wave LDS.
// No running max: scores are O(1), exp(-1e9)=0 handles masking exactly.
// q: [B,H,S,64] bf16 pre-scaled 0.125; k: [B,H,S,64]; vt: [B,H,64,S].
// ---------------------------------------------------------------------------
__global__ __launch_bounds__(256) void attn_mfma(
    const u16* __restrict__ q_g, const u16* __restrict__ k_g,
    const u16* __restrict__ vt_g, const float* __restrict__ mask,
    u16* __restrict__ ab, int halfw)
{
  __shared__ __align__(16) u16 lsP[4][640];   // per wave [16 q][32 keys pad 40]

  const int b = blockIdx.z, h = blockIdx.y;
  const int bh = b * 12 + h;
  const int wave = threadIdx.x >> 6, lane = threadIdx.x & 63;
  const int quad = lane >> 4, l16 = lane & 15;
  const int qw0 = blockIdx.x * 64 + wave * 16;

  const size_t qrow = ((size_t)bh * 2048 + qw0 + l16) * 64 + quad * 8;
  const short8 qf0 = *(const short8*)(q_g + qrow);
  const short8 qf1 = *(const short8*)(q_g + qrow + 32);

  floatx4 oacc[4] = {};
  float lrow[4] = {0.f, 0.f, 0.f, 0.f};
  u16* Pw = lsP[wave];

  const int klo = ((qw0 - halfw > 0) ? (qw0 - halfw) : 0) & ~31;
  const int khi = (qw0 + 15 + halfw < 2047) ? (qw0 + 15 + halfw) : 2047;

  for (int k0 = klo; k0 <= khi; k0 += 32) {
    // scores: 2 MFMA per 16-key tile (dims 0-31, 32-63)
    floatx4 sc[2];
#pragma unroll
    for (int ct = 0; ct < 2; ++ct) {
      const size_t kr = ((size_t)bh * 2048 + k0 + ct * 16 + l16) * 64 + quad * 8;
      const short8 kf0 = *(const short8*)(k_g + kr);
      const short8 kf1 = *(const short8*)(k_g + kr + 32);
      floatx4 sa = {};
      sa = __builtin_amdgcn_mfma_f32_16x16x32_bf16(qf0, kf0, sa, 0, 0, 0);
      sa = __builtin_amdgcn_mfma_f32_16x16x32_bf16(qf1, kf1, sa, 0, 0, 0);
      sc[ct] = sa;
    }
    // band+mask select (garbage K beyond S never escapes the select), exp
    float pr[2][4];
#pragma unroll
    for (int ct = 0; ct < 2; ++ct) {
      const int g = k0 + ct * 16 + l16;
      const int gc = (g < 2047) ? g : 2047;
      const float ma = (1.0f - mask[b * 2048 + gc]) * -1.0e9f;
#pragma unroll
      for (int r = 0; r < 4; ++r) {
        const int t = qw0 + quad * 4 + r;
        const bool valid = (g >= t - halfw) && (g <= t + halfw) && (g < 2048);
        pr[ct][r] = __expf(valid ? sc[ct][r] + ma : -1.0e9f);
      }
    }
#pragma unroll
    for (int r = 0; r < 4; ++r) {
      float rs = pr[0][r] + pr[1][r];
      rs += __shfl_xor(rs, 1, 64);
      rs += __shfl_xor(rs, 2, 64);
      rs += __shfl_xor(rs, 4, 64);
      rs += __shfl_xor(rs, 8, 64);
      lrow[r] += rs;
    }
    // P: C-layout -> per-wave LDS -> A-layout (intra-wave dep only)
#pragma unroll
    for (int ct = 0; ct < 2; ++ct)
#pragma unroll
      for (int r = 0; r < 4; ++r)
        Pw[(quad * 4 + r) * 40 + ct * 16 + l16] = f2bf(pr[ct][r]);
    const short8 pa = *(const short8*)(Pw + l16 * 40 + quad * 8);
    // PV: B-fragments straight from global VT (p=0 kills any OOB garbage)
#pragma unroll
    for (int dt = 0; dt < 4; ++dt) {
      const size_t vr = ((size_t)bh * 64 + dt * 16 + l16) * 2048 + k0 + quad * 8;
      const short8 vf = *(const short8*)(vt_g + vr);
      oacc[dt] = __builtin_amdgcn_mfma_f32_16x16x32_bf16(pa, vf, oacc[dt], 0, 0, 0);
    }
  }

#pragma unroll
  for (int r = 0; r < 4; ++r) {
    const float inv = 1.0f / lrow[r];
    const size_t orow = ((size_t)b * 2048 + qw0 + quad * 4 + r) * 768 + h * 64;
#pragma unroll
    for (int dt = 0; dt < 4; ++dt)
      ab[orow + dt * 16 + l16] = f2bf(oacc[dt][r] * inv);
  }
}

// ---------------------------------------------------------------------------
// Embedding gather + LayerNorm. block per token (4096 blocks, 256 thr)
// ---------------------------------------------------------------------------
__global__ __launch_bounds__(256) void embed_ln_kernel(
    const int* __restrict__ ids, const float* __restrict__ wemb, const float* __restrict__ pemb,
    const float* __restrict__ temb, const float* __restrict__ g, const float* __restrict__ be,
    float* __restrict__ x, u16* __restrict__ xb)
{
  const int t = blockIdx.x;
  const int s = t & 2047;
  const int id = ids[t];
  const int tid = threadIdx.x;
  const int wave = tid >> 6, lane = tid & 63;

  float vals[3]; float sum = 0.f, ssq = 0.f;
#pragma unroll
  for (int i = 0; i < 3; ++i) {
    const int d = tid + i * 256;
    const float v = wemb[(size_t)id * 768 + d] + pemb[(size_t)(s + 2) * 768 + d] + temb[d];
    vals[i] = v; sum += v; ssq += v * v;
  }
#pragma unroll
  for (int off = 32; off; off >>= 1) { sum += __shfl_xor(sum, off, 64); ssq += __shfl_xor(ssq, off, 64); }
  __shared__ float rb[8];
  if (lane == 0) { rb[wave] = sum; rb[4 + wave] = ssq; }
  __syncthreads();
  sum = rb[0] + rb[1] + rb[2] + rb[3];
  ssq = rb[4] + rb[5] + rb[6] + rb[7];
  const float mu = sum * (1.f / 768.f);
  const float var = ssq * (1.f / 768.f) - mu * mu;
  const float rstd = rsqrtf(var + 1e-5f);
#pragma unroll
  for (int i = 0; i < 3; ++i) {
    const int d = tid + i * 256;
    const float o = (vals[i] - mu) * rstd * g[d] + be[d];
    x[(size_t)t * 768 + d] = o;
    xb[(size_t)t * 768 + d] = f2bf(o);
  }
}

// ---------------------------------------------------------------------------
// Split-K reduce + bias + residual + LayerNorm. block per token.
// ---------------------------------------------------------------------------
template<int NC>
__global__ __launch_bounds__(256) void reduce_ln_kernel(
    const float* __restrict__ pb, const float* __restrict__ bias,
    const float* __restrict__ g, const float* __restrict__ be,
    float* x, u16* __restrict__ xb)
{
  const int t = blockIdx.x;
  const int tid = threadIdx.x;
  const int wave = tid >> 6, lane = tid & 63;

  float vals[3]; float sum = 0.f, ssq = 0.f;
#pragma unroll
  for (int i = 0; i < 3; ++i) {
    const int d = tid + i * 256;
    float v = x[(size_t)t * 768 + d] + bias[d];
#pragma unroll
    for (int c = 0; c < NC; ++c)
      v += pb[((size_t)c * 4096 + t) * 768 + d];
    vals[i] = v; sum += v; ssq += v * v;
  }
#pragma unroll
  for (int off = 32; off; off >>= 1) { sum += __shfl_xor(sum, off, 64); ssq += __shfl_xor(ssq, off, 64); }
  __shared__ float rb[8];
  if (lane == 0) { rb[wave] = sum; rb[4 + wave] = ssq; }
  __syncthreads();
  sum = rb[0] + rb[1] + rb[2] + rb[3];
  ssq = rb[4] + rb[5] + rb[6] + rb[7];
  const float mu = sum * (1.f / 768.f);
  const float var = ssq * (1.f / 768.f) - mu * mu;
  const float rstd = rsqrtf(var + 1e-5f);
#pragma unroll
  for (int i = 0; i < 3; ++i) {
    const int d = tid + i * 256;
    const float o = (vals[i] - mu) * rstd * g[d] + be[d];
    x[(size_t)t * 768 + d] = o;
    xb[(size_t)t * 768 + d] = f2bf(o);
  }
}

// ---------------------------------------------------------------------------
// Head: out[b] = dot(x[b,0,:], Wtop[0:768]) + fts[b]*Wtop[768] + btop
// ---------------------------------------------------------------------------
__global__ __launch_bounds__(256) void head_kernel(
    const float* __restrict__ x, const float* __restrict__ fts,
    const float* __restrict__ wtop, const float* __restrict__ btop, float* __restrict__ out)
{
  const int tid = threadIdx.x;
  const int wave = tid >> 6, lane = tid & 63;
  __shared__ float rb[4];
  for (int b = 0; b < 2; ++b) {
    float s = 0.f;
    for (int d = tid; d < 768; d += 256)
      s += x[(size_t)b * 2048 * 768 + d] * wtop[d];
#pragma unroll
    for (int off = 32; off; off >>= 1) s += __shfl_xor(s, off, 64);
    if (lane == 0) rb[wave] = s;
    __syncthreads();
    if (tid == 0) {
      float r = rb[0] + rb[1] + rb[2] + rb[3];
      r += fts[b] * wtop[768] + btop[0];
      out[b] = r;
    }
    __syncthreads();
  }
}

// ---------------------------------------------------------------------------
extern "C" void kernel_launch(void* const* d_in, const int* in_sizes, int n_in,
                              void* d_out, int out_size, void* d_ws, size_t ws_size,
                              hipStream_t stream)
{
  const int*   ids  = (const int*)d_in[0];
  const float* mask = (const float*)d_in[1];
  const float* fts  = (const float*)d_in[2];
  const float* wemb = (const float*)d_in[3];
  const float* pemb = (const float*)d_in[4];
  const float* temb = (const float*)d_in[5];
  const float* lneg = (const float*)d_in[6];
  const float* lneb = (const float*)d_in[7];
  const float* Wq   = (const float*)d_in[8];
  const float* bq   = (const float*)d_in[9];
  const float* Wk   = (const float*)d_in[10];
  const float* bk   = (const float*)d_in[11];
  const float* Wv   = (const float*)d_in[12];
  const float* bvv  = (const float*)d_in[13];
  const float* Wo   = (const float*)d_in[14];
  const float* bo   = (const float*)d_in[15];
  const float* ln1g = (const float*)d_in[16];
  const float* ln1b = (const float*)d_in[17];
  const float* W1   = (const float*)d_in[18];
  const float* b1   = (const float*)d_in[19];
  const float* W2   = (const float*)d_in[20];
  const float* b2   = (const float*)d_in[21];
  const float* ln2g = (const float*)d_in[22];
  const float* ln2b = (const float*)d_in[23];
  const float* wtop = (const float*)d_in[24];
  const float* btop = (const float*)d_in[25];

  const size_t SQ   = 768 * 768;
  const size_t SQ3  = 2304 * 768;
  const size_t SF   = 3072 * 768;
  const size_t perL = SQ3 + SQ + 2 * SF;
  const size_t NTOK = 4096;
  const size_t HDSZ = (size_t)2 * 12 * 2048 * 64;   // per q/k/vt buffer elems
  const size_t PAD  = 4096;                          // band-edge overread pad

  const size_t fixedBytes =
      NTOK * 768 * 4          // x
    + NTOK * 768 * 2          // xb
    + 4 * NTOK * 768 * 4      // pb (split-K partials)
    + NTOK * 768 * 2          // ab
    + NTOK * 3072 * 2         // hb
    + 3 * (HDSZ + PAD) * 2;   // qB,kB,vtB
  const bool batched = ws_size >= fixedBytes + 12 * perL * 2 + 65536;
  const size_t nw = batched ? 12 : 1;

  char* p = (char*)d_ws;
  u16* wTqkv = (u16*)p; p += nw * SQ3 * 2;
  u16* wTo   = (u16*)p; p += nw * SQ  * 2;
  u16* wT1   = (u16*)p; p += nw * SF  * 2;
  u16* wT2   = (u16*)p; p += nw * SF  * 2;
  float* x  = (float*)p; p += NTOK * 768 * 4;
  u16*   xb = (u16*)p;   p += NTOK * 768 * 2;
  float* pb = (float*)p; p += 4 * NTOK * 768 * 4;
  u16*   ab = (u16*)p;   p += NTOK * 768 * 2;
  u16*   hb = (u16*)p;   p += NTOK * 3072 * 2;
  u16*   qB  = (u16*)p;  p += (HDSZ + PAD) * 2;
  u16*   kB  = (u16*)p;  p += (HDSZ + PAD) * 2;
  u16*   vtB = (u16*)p;  p += (HDSZ + PAD) * 2;

  if (batched) {
    transpose_cvt<<<dim3(24, 24, 12), 256, 0, stream>>>(Wq, wTqkv,             768, 768,  SQ, SQ3);
    transpose_cvt<<<dim3(24, 24, 12), 256, 0, stream>>>(Wk, wTqkv + 768 * 768, 768, 768,  SQ, SQ3);
    transpose_cvt<<<dim3(24, 24, 12), 256, 0, stream>>>(Wv, wTqkv + 1536 * 768,768, 768,  SQ, SQ3);
    transpose_cvt<<<dim3(24, 24, 12), 256, 0, stream>>>(Wo, wTo, 768, 768,  SQ, SQ);
    transpose_cvt<<<dim3(96, 24, 12), 256, 0, stream>>>(W1, wT1, 768, 3072, SF, SF);
    transpose_cvt<<<dim3(24, 96, 12), 256, 0, stream>>>(W2, wT2, 3072, 768, SF, SF);
  }

  embed_ln_kernel<<<4096, 256, 0, stream>>>(ids, wemb, pemb, temb, lneg, lneb, x, xb);

  for (int i = 0; i < 12; ++i) {
    const u16 *WqkvTl, *WoTl, *W1Tl, *W2Tl;
    if (batched) {
      WqkvTl = wTqkv + (size_t)i * SQ3; WoTl = wTo + (size_t)i * SQ;
      W1Tl = wT1 + (size_t)i * SF;      W2Tl = wT2 + (size_t)i * SF;
    } else {
      transpose_cvt<<<dim3(24, 24, 1), 256, 0, stream>>>(Wq + (size_t)i * SQ, wTqkv,             768, 768, SQ, SQ3);
      transpose_cvt<<<dim3(24, 24, 1), 256, 0, stream>>>(Wk + (size_t)i * SQ, wTqkv + 768 * 768, 768, 768, SQ, SQ3);
      transpose_cvt<<<dim3(24, 24, 1), 256, 0, stream>>>(Wv + (size_t)i * SQ, wTqkv + 1536 * 768,768, 768, SQ, SQ3);
      transpose_cvt<<<dim3(24, 24, 1), 256, 0, stream>>>(Wo + (size_t)i * SQ, wTo, 768, 768, SQ, SQ);
      transpose_cvt<<<dim3(96, 24, 1), 256, 0, stream>>>(W1 + (size_t)i * SF, wT1, 768, 3072, SF, SF);
      transpose_cvt<<<dim3(24, 96, 1), 256, 0, stream>>>(W2 + (size_t)i * SF, wT2, 3072, 768, SF, SF);
      WqkvTl = wTqkv; WoTl = wTo; W1Tl = wT1; W2Tl = wT2;
    }

    // fused QKV projection: [4096,768] @ [768,2304] -> q,k,[B,H,S,64]; vt [B,H,64,S]
    gemm_bt<3><<<dim3(18, 32), 256, 0, stream>>>(
        xb, WqkvTl, bq + (size_t)i * 768, bk + (size_t)i * 768, bvv + (size_t)i * 768,
        nullptr, nullptr, qB, kB, vtB, 4096, 2304, 768, 768);

    attn_mfma<<<dim3(32, 12, 2), 256, 0, stream>>>(qB, kB, vtB, mask, ab, g_halves[i]);

    // out-proj: split-K=2 -> partials, then reduce+residual+LN
    gemm_bt<4><<<dim3(6, 32, 2), 256, 0, stream>>>(
        ab, WoTl, nullptr, nullptr, nullptr, pb, nullptr,
        nullptr, nullptr, nullptr, 4096, 768, 768, 384);
    reduce_ln_kernel<2><<<4096, 256, 0, stream>>>(
        pb, bo + (size_t)i * 768, ln1g + (size_t)i * 768, ln1b + (size_t)i * 768, x, xb);

    // FFN1: 256x256 8-phase GEMM, gelu epilogue
    gemm8p<2><<<dim3(12, 16), 512, 0, stream>>>(
        xb, W1Tl, b1 + (size_t)i * 3072, nullptr, hb, 4096, 3072, 768, 768);

    // FFN2: 256x256 8-phase GEMM, split-K=4 -> partials, then reduce+residual+LN
    gemm8p<4><<<dim3(3, 16, 4), 512, 0, stream>>>(
        hb, W2Tl, nullptr, pb, nullptr, 4096, 768, 3072, 768);
    reduce_ln_kernel<4><<<4096, 256, 0, stream>>>(
        pb, b2 + (size_t)i * 768, ln2g + (size_t)i * 768, ln2b + (size_t)i * 768, x, xb);
  }

  head_kernel<<<1, 256, 0, stream>>>(x, fts, wtop, btop, (float*)d_out);
}

// Round 4
// 2565.126 us; speedup vs baseline: 1.1463x; 1.1463x over previous
//
#include <hip/hip_runtime.h>

typedef unsigned short u16;
using short8   = __attribute__((ext_vector_type(8))) short;
using floatx4  = __attribute__((ext_vector_type(4))) float;
using ushortx4 = __attribute__((ext_vector_type(4))) unsigned short;

// window one-sided sizes per layer (WINDOWS/2)
static const int g_halves[12] = {16,16,32,32,64,64,128,128,256,256,256,256};

__device__ __forceinline__ float bf2f(u16 u) {
  union { unsigned int i; float f; } x; x.i = ((unsigned int)u) << 16; return x.f;
}
__device__ __forceinline__ u16 f2bf(float f) {
  union { float f; unsigned int i; } x; x.f = f;
  unsigned int r = x.i + 0x7FFFu + ((x.i >> 16) & 1u);
  return (u16)(r >> 16);
}

// async 16B/lane global->LDS; dest is wave-uniform base, lane l lands at base + l*16
__device__ __forceinline__ void gld_lds16(const u16* g, u16* l) {
  __builtin_amdgcn_global_load_lds(
      (const __attribute__((address_space(1))) unsigned int*)g,
      (__attribute__((address_space(3))) unsigned int*)l, 16, 0, 0);
}

// inline-asm ds_read_b128: invisible to SIInsertWaitcnts' LDS-DMA alias
// tracking, so no compiler-inserted vmcnt drains before LDS reads. Callers
// MUST order consumption via explicit s_waitcnt lgkmcnt + sched_barrier(0).
__device__ __forceinline__ short8 ds_read_b128s(const u16* p) {
  short8 r;
  const __attribute__((address_space(3))) u16* lp =
      (const __attribute__((address_space(3))) u16*)p;
  asm volatile("ds_read_b128 %0, %1" : "=v"(r) : "v"(lp));
  return r;
}

// ---------------------------------------------------------------------------
// fused transpose + f32->bf16 convert: in f32 [z][R][C] -> out bf16 [z][C][R]
// ---------------------------------------------------------------------------
__global__ __launch_bounds__(256) void transpose_cvt(
    const float* __restrict__ in, u16* __restrict__ out, int R, int C,
    size_t inZ, size_t outZ)
{
  __shared__ u16 t[32][33];
  const int tx = threadIdx.x & 31, ty = threadIdx.x >> 5; // 32 x 8
  const size_t bi = (size_t)blockIdx.z * inZ;
  const size_t bo = (size_t)blockIdx.z * outZ;
  const int r0 = blockIdx.y * 32, c0 = blockIdx.x * 32;
#pragma unroll
  for (int j = 0; j < 32; j += 8)
    t[ty + j][tx] = f2bf(in[bi + (size_t)(r0 + ty + j) * C + (c0 + tx)]);
  __syncthreads();
#pragma unroll
  for (int j = 0; j < 32; j += 8)
    out[bo + (size_t)(c0 + ty + j) * R + (r0 + tx)] = t[tx][ty + j];
}

// ---------------------------------------------------------------------------
// GEMM: C[M,N] = A[M,K](bf16) @ B[K,N] given as Bt[N,K](bf16)
// EPI 2: outB = bf16(gelu_exact(acc+bias))
// EPI 3: QKV fused: N=2304; seg0=Q*0.125 -> qg [B,H,S,64]; seg1=K -> kg
//        [B,H,S,64]; seg2=V -> vt [B,H,64,S] (transposed, packed 8B stores)
// EPI 4: split-K partial: outF[(z*M+row)*N+col] = acc
// ---------------------------------------------------------------------------
template<int EPI>
__global__ __launch_bounds__(256) void gemm_bt(
    const u16* __restrict__ A, const u16* __restrict__ Bt,
    const float* __restrict__ biasA, const float* __restrict__ biasB, const float* __restrict__ biasC,
    float* __restrict__ outF, u16* __restrict__ outB,
    u16* __restrict__ qg, u16* __restrict__ kg, u16* __restrict__ vt,
    int M, int N, int K, int KC)
{
  __shared__ __align__(16) u16 lsA[128 * 32];
  __shared__ __align__(16) u16 lsB[128 * 32];
  const int tid  = threadIdx.x;
  const int wave = tid >> 6, lane = tid & 63;
  const int quad = lane >> 4, l16 = lane & 15;
  const int m0 = blockIdx.y * 128, n0 = blockIdx.x * 128;
  const int kz = blockIdx.z * KC;
  const int wm = (wave >> 1) * 64, wn = (wave & 1) * 64;
  const int srow = lane >> 2;          // row within 16-row chunk
  const int skof = (lane & 3) * 8;     // bf16 offset along k

  floatx4 acc[4][4] = {};

  for (int k0 = kz; k0 < kz + KC; k0 += 32) {
    __syncthreads();
#pragma unroll
    for (int c = wave; c < 16; c += 4) {
      if (c < 8)
        gld_lds16(A  + (size_t)(m0 + c * 16 + srow) * K + k0 + skof, lsA + c * 512);
      else
        gld_lds16(Bt + (size_t)(n0 + (c - 8) * 16 + srow) * K + k0 + skof, lsB + (c - 8) * 512);
    }
    __syncthreads();
    short8 af[4], bfr[4];
#pragma unroll
    for (int i = 0; i < 4; ++i)
      af[i]  = *(const short8*)(lsA + (wm + i * 16 + l16) * 32 + quad * 8);
#pragma unroll
    for (int j = 0; j < 4; ++j)
      bfr[j] = *(const short8*)(lsB + (wn + j * 16 + l16) * 32 + quad * 8);
#pragma unroll
    for (int i = 0; i < 4; ++i)
#pragma unroll
      for (int j = 0; j < 4; ++j)
        acc[i][j] = __builtin_amdgcn_mfma_f32_16x16x32_bf16(af[i], bfr[j], acc[i][j], 0, 0, 0);
  }

#pragma unroll
  for (int i = 0; i < 4; ++i)
#pragma unroll
    for (int j = 0; j < 4; ++j) {
      const int col = n0 + wn + j * 16 + l16;
      if (EPI == 3) {
        const int seg = (col >= 1536) ? 2 : (col >= 768) ? 1 : 0;
        const int cc = col - seg * 768;
        const int hh = cc >> 6, dd = cc & 63;
        const float bvl = (seg == 0) ? biasA[cc] : (seg == 1) ? biasB[cc] : biasC[cc];
        const int row0 = m0 + wm + i * 16 + quad * 4;
        const int bI = row0 >> 11, ss = row0 & 2047;
        const int bh = bI * 12 + hh;
        if (seg == 2) {
          ushortx4 pk;
#pragma unroll
          for (int r = 0; r < 4; ++r) pk[r] = f2bf(acc[i][j][r] + bvl);
          *(ushortx4*)(vt + ((size_t)bh * 64 + dd) * 2048 + ss) = pk;
        } else {
          u16* dst = (seg == 0) ? qg : kg;
          const float scl = (seg == 0) ? 0.125f : 1.0f;
#pragma unroll
          for (int r = 0; r < 4; ++r)
            dst[((size_t)bh * 2048 + ss + r) * 64 + dd] = f2bf((acc[i][j][r] + bvl) * scl);
        }
      } else if (EPI == 2) {
        const float bvl = biasA[col];
#pragma unroll
        for (int r = 0; r < 4; ++r) {
          const int row = m0 + wm + i * 16 + quad * 4 + r;
          const size_t idx = (size_t)row * N + col;
          float v = acc[i][j][r] + bvl;
          v = 0.5f * v * (1.0f + erff(v * 0.70710678118654752f));
          outB[idx] = f2bf(v);
        }
      } else { // EPI == 4
#pragma unroll
        for (int r = 0; r < 4; ++r) {
          const int row = m0 + wm + i * 16 + quad * 4 + r;
          outF[((size_t)blockIdx.z * M + row) * N + col] = acc[i][j][r];
        }
      }
    }
}

// ---------------------------------------------------------------------------
// 256x256 8-phase GEMM v2.  Diff vs v1 (which measured 109us, MfmaUtil 6.7%):
//  - ds_reads now inline-asm (ds_read_b128s): the compiler's LDS-DMA alias
//    tracking was inserting near-drain vmcnt waits before every plain-C
//    ds_read of `ls`, serializing each phase on the t+2 prefetches.  With asm
//    reads the only waits are OUR counted ones.
//  - every MFMA cluster is guarded by explicit s_waitcnt lgkmcnt(0) +
//    sched_barrier(0)  (rule #18: required with asm ds_read).
//  - STG issued at top of phase (T3 recipe ordering).
//  - bijective XCD swizzle on (bx,by)  (nwg 192/48, both %8==0).
// Schedule per K-tile t (buffer cur=t&1):
//   ph0: stage A0(t+1)->cur^1; asm-read A-frags i0-3 + B-frags j0-1;
//        bar; lgkm0; 16 MFMA; bar
//   ph1: stage A1(t+1)->cur^1; asm-read B-frags j2-3; bar; lgkm0; 16 MFMA; bar
//   ph2: stage B0(t+2)->cur;   asm-read A-frags i4-7; bar; lgkm0; 16 MFMA; bar
//   ph3: stage B1(t+2)->cur;   bar; 16 MFMA (operands already waited);
//        s_waitcnt vmcnt(4); bar   // tile t+1's 4 halves complete; the 4
//                                  // still in flight are B0/B1(t+2)
// Slot-safety unchanged from v1 (every LDS slot overwritten >=1 barrier
// phase after its last read; barrier after the vmcnt makes the per-wave
// guarantee collective).
// ---------------------------------------------------------------------------
template<int EPI>
__global__ __launch_bounds__(512, 2) void gemm8p(
    const u16* __restrict__ A, const u16* __restrict__ Bt,
    const float* __restrict__ bias,
    float* __restrict__ outF, u16* __restrict__ outB,
    int M, int N, int K, int KC)
{
  __shared__ __align__(16) u16 ls[2][2][2][8192];   // [buf][op A/B][half][128*64]
  const int tid  = threadIdx.x;
  const int wave = tid >> 6, lane = tid & 63;
  const int quad = lane >> 4, l16 = lane & 15;
  const int lr   = l16 & 7;

  // bijective XCD swizzle: hardware id hid -> logical tile swz; XCD k gets a
  // contiguous chunk of logical tiles -> neighbor tiles share L2 panels.
  const int nwg  = gridDim.x * gridDim.y;
  const int hid  = blockIdx.y * gridDim.x + blockIdx.x;
  const int cpx  = nwg >> 3;
  const int swz  = (hid & 7) * cpx + (hid >> 3);
  const int bx   = swz % gridDim.x, by = swz / gridDim.x;

  const int m0 = by * 256, n0 = bx * 256;
  const int kz = blockIdx.z * KC;
  const int NT = KC >> 6;

  const int ha  = wave >> 2;         // this wave's A half
  const int hbw = (wave >> 1) & 1;   // this wave's B half
  const int cb  = (wave & 1) * 64;   // col base within B half
  const int wm  = (wave >> 2) * 128; // output row base
  const int wn  = (wave & 3) * 64;   // output col base

  // staging geometry: global 16B-chunk g = (ii*8+wave)*64+lane; row=g>>3;
  // source k-chunk = (g&7) ^ (row&7)  (inverse swizzle at the source)
  int srow[2], soff[2];
#pragma unroll
  for (int ii = 0; ii < 2; ++ii) {
    const int g = (ii * 8 + wave) * 64 + lane;
    srow[ii] = g >> 3;
    soff[ii] = ((g & 7) ^ (srow[ii] & 7)) * 8;
  }
  // ds_read swizzled chunk offset for ks=0/1: chunk (ks*4+quad) ^ (row&7)
  int cs[2];
#pragma unroll
  for (int ks = 0; ks < 2; ++ks) cs[ks] = (((ks << 2) | quad) ^ lr) * 8;

  floatx4 acc[8][4] = {};
  short8 af[4][2];   // current i-group (4 m-frags x 2 k-slices)
  short8 bf[4][2];   // all 4 n-frags x 2 k-slices (held across the tile)

#define STG(buf, op, half, base, rb, kc) do { \
  _Pragma("unroll") \
  for (int ii = 0; ii < 2; ++ii) \
    gld_lds16((base) + (size_t)((rb) + (half) * 128 + srow[ii]) * K + (kc) + soff[ii], \
              &ls[buf][op][half][(ii * 8 + wave) * 512]); \
} while (0)

#define RDA(ig) do { \
  _Pragma("unroll") \
  for (int ii = 0; ii < 4; ++ii) \
  _Pragma("unroll") \
  for (int ks = 0; ks < 2; ++ks) \
    af[ii][ks] = ds_read_b128s(&ls[cur][0][ha][(((ig) * 4 + ii) * 16 + l16) * 64 + cs[ks]]); \
} while (0)

#define RDB(jg) do { \
  _Pragma("unroll") \
  for (int jj = 0; jj < 2; ++jj) \
  _Pragma("unroll") \
  for (int ks = 0; ks < 2; ++ks) \
    bf[(jg) * 2 + jj][ks] = ds_read_b128s(&ls[cur][1][hbw][(cb + ((jg) * 2 + jj) * 16 + l16) * 64 + cs[ks]]); \
} while (0)

#define LGKM0() do { \
  asm volatile("s_waitcnt lgkmcnt(0)" ::: "memory"); \
  __builtin_amdgcn_sched_barrier(0); \
} while (0)

#define MM(ILO, JLO) do { \
  __builtin_amdgcn_s_setprio(1); \
  _Pragma("unroll") \
  for (int ii = 0; ii < 4; ++ii) \
  _Pragma("unroll") \
  for (int jj = 0; jj < 2; ++jj) \
  _Pragma("unroll") \
  for (int ks = 0; ks < 2; ++ks) \
    acc[(ILO) + ii][(JLO) + jj] = __builtin_amdgcn_mfma_f32_16x16x32_bf16( \
        af[ii][ks], bf[(JLO) + jj][ks], acc[(ILO) + ii][(JLO) + jj], 0, 0, 0); \
  __builtin_amdgcn_s_setprio(0); \
} while (0)

  // prologue issue order (FIFO matters for the vmcnt accounting):
  // B0(0),B1(0),A0(0),A1(0),B0(1),B1(1) -> tile0's 4 halves are the oldest 8
  STG(0, 1, 0, Bt, n0, kz); STG(0, 1, 1, Bt, n0, kz);
  STG(0, 0, 0, A,  m0, kz); STG(0, 0, 1, A,  m0, kz);
  STG(1, 1, 0, Bt, n0, kz + 64); STG(1, 1, 1, Bt, n0, kz + 64);
  asm volatile("s_waitcnt vmcnt(4)" ::: "memory");
  __builtin_amdgcn_s_barrier();

  int cur = 0;
  for (int t = 0; t < NT; ++t, cur ^= 1) {
    const int k1 = kz + (t + 1) * 64;
    const int k2 = k1 + 64;
    const bool s1 = (t + 1 < NT), s2 = (t + 2 < NT);
    // phase 0
    if (s1) STG(cur ^ 1, 0, 0, A, m0, k1);
    RDA(0); RDB(0);
    __builtin_amdgcn_s_barrier();
    LGKM0();
    MM(0, 0);
    __builtin_amdgcn_s_barrier();
    // phase 1
    if (s1) STG(cur ^ 1, 0, 1, A, m0, k1);
    RDB(1);
    __builtin_amdgcn_s_barrier();
    LGKM0();
    MM(0, 2);
    __builtin_amdgcn_s_barrier();
    // phase 2
    if (s2) STG(cur, 1, 0, Bt, n0, k2);
    RDA(1);
    __builtin_amdgcn_s_barrier();
    LGKM0();
    MM(4, 2);
    __builtin_amdgcn_s_barrier();
    // phase 3 (operands af=ph2, bf[0:1]=ph0 -- already lgkm-waited)
    if (s2) STG(cur, 1, 1, Bt, n0, k2);
    __builtin_amdgcn_s_barrier();
    MM(4, 0);
    if (s2) asm volatile("s_waitcnt vmcnt(4)" ::: "memory");
    else    asm volatile("s_waitcnt vmcnt(0)" ::: "memory");
    __builtin_amdgcn_s_barrier();
  }
#undef STG
#undef RDA
#undef RDB
#undef LGKM0
#undef MM

#pragma unroll
  for (int i = 0; i < 8; ++i)
#pragma unroll
    for (int j = 0; j < 4; ++j) {
      const int col  = n0 + wn + j * 16 + l16;
      const int row0 = m0 + wm + i * 16 + quad * 4;
      if (EPI == 2) {
        const float bvl = bias[col];
#pragma unroll
        for (int r = 0; r < 4; ++r) {
          float v = acc[i][j][r] + bvl;
          v = 0.5f * v * (1.0f + erff(v * 0.70710678118654752f));
          outB[(size_t)(row0 + r) * N + col] = f2bf(v);
        }
      } else { // EPI == 4
#pragma unroll
        for (int r = 0; r < 4; ++r)
          outF[((size_t)blockIdx.z * M + row0 + r) * N + col] = acc[i][j][r];
      }
    }
}

// ---------------------------------------------------------------------------
// MFMA banded flash attention, barrier-free. grid (S/64, H, B), 256 thr =
// 4 independent waves x 16 queries. K/Q/VT fragments load directly from
// global (coalesced 16B/lane, L2-served); only P round-trips per-wave LDS.
// No running max: scores are O(1), exp(-1e9)=0 handles masking exactly.
// q: [B,H,S,64] bf16 pre-scaled 0.125; k: [B,H,S,64]; vt: [B,H,64,S].
// ---------------------------------------------------------------------------
__global__ __launch_bounds__(256) void attn_mfma(
    const u16* __restrict__ q_g, const u16* __restrict__ k_g,
    const u16* __restrict__ vt_g, const float* __restrict__ mask,
    u16* __restrict__ ab, int halfw)
{
  __shared__ __align__(16) u16 lsP[4][640];   // per wave [16 q][32 keys pad 40]

  const int b = blockIdx.z, h = blockIdx.y;
  const int bh = b * 12 + h;
  const int wave = threadIdx.x >> 6, lane = threadIdx.x & 63;
  const int quad = lane >> 4, l16 = lane & 15;
  const int qw0 = blockIdx.x * 64 + wave * 16;

  const size_t qrow = ((size_t)bh * 2048 + qw0 + l16) * 64 + quad * 8;
  const short8 qf0 = *(const short8*)(q_g + qrow);
  const short8 qf1 = *(const short8*)(q_g + qrow + 32);

  floatx4 oacc[4] = {};
  float lrow[4] = {0.f, 0.f, 0.f, 0.f};
  u16* Pw = lsP[wave];

  const int klo = ((qw0 - halfw > 0) ? (qw0 - halfw) : 0) & ~31;
  const int khi = (qw0 + 15 + halfw < 2047) ? (qw0 + 15 + halfw) : 2047;

  for (int k0 = klo; k0 <= khi; k0 += 32) {
    // scores: 2 MFMA per 16-key tile (dims 0-31, 32-63)
    floatx4 sc[2];
#pragma unroll
    for (int ct = 0; ct < 2; ++ct) {
      const size_t kr = ((size_t)bh * 2048 + k0 + ct * 16 + l16) * 64 + quad * 8;
      const short8 kf0 = *(const short8*)(k_g + kr);
      const short8 kf1 = *(const short8*)(k_g + kr + 32);
      floatx4 sa = {};
      sa = __builtin_amdgcn_mfma_f32_16x16x32_bf16(qf0, kf0, sa, 0, 0, 0);
      sa = __builtin_amdgcn_mfma_f32_16x16x32_bf16(qf1, kf1, sa, 0, 0, 0);
      sc[ct] = sa;
    }
    // band+mask select (garbage K beyond S never escapes the select), exp
    float pr[2][4];
#pragma unroll
    for (int ct = 0; ct < 2; ++ct) {
      const int g = k0 + ct * 16 + l16;
      const int gc = (g < 2047) ? g : 2047;
      const float ma = (1.0f - mask[b * 2048 + gc]) * -1.0e9f;
#pragma unroll
      for (int r = 0; r < 4; ++r) {
        const int t = qw0 + quad * 4 + r;
        const bool valid = (g >= t - halfw) && (g <= t + halfw) && (g < 2048);
        pr[ct][r] = __expf(valid ? sc[ct][r] + ma : -1.0e9f);
      }
    }
#pragma unroll
    for (int r = 0; r < 4; ++r) {
      float rs = pr[0][r] + pr[1][r];
      rs += __shfl_xor(rs, 1, 64);
      rs += __shfl_xor(rs, 2, 64);
      rs += __shfl_xor(rs, 4, 64);
      rs += __shfl_xor(rs, 8, 64);
      lrow[r] += rs;
    }
    // P: C-layout -> per-wave LDS -> A-layout (intra-wave dep only)
#pragma unroll
    for (int ct = 0; ct < 2; ++ct)
#pragma unroll
      for (int r = 0; r < 4; ++r)
        Pw[(quad * 4 + r) * 40 + ct * 16 + l16] = f2bf(pr[ct][r]);
    const short8 pa = *(const short8*)(Pw + l16 * 40 + quad * 8);
    // PV: B-fragments straight from global VT (p=0 kills any OOB garbage)
#pragma unroll
    for (int dt = 0; dt < 4; ++dt) {
      const size_t vr = ((size_t)bh * 64 + dt * 16 + l16) * 2048 + k0 + quad * 8;
      const short8 vf = *(const short8*)(vt_g + vr);
      oacc[dt] = __builtin_amdgcn_mfma_f32_16x16x32_bf16(pa, vf, oacc[dt], 0, 0, 0);
    }
  }

#pragma unroll
  for (int r = 0; r < 4; ++r) {
    const float inv = 1.0f / lrow[r];
    const size_t orow = ((size_t)b * 2048 + qw0 + quad * 4 + r) * 768 + h * 64;
#pragma unroll
    for (int dt = 0; dt < 4; ++dt)
      ab[orow + dt * 16 + l16] = f2bf(oacc[dt][r] * inv);
  }
}

// ---------------------------------------------------------------------------
// Embedding gather + LayerNorm. block per token (4096 blocks, 256 thr)
// ---------------------------------------------------------------------------
__global__ __launch_bounds__(256) void embed_ln_kernel(
    const int* __restrict__ ids, const float* __restrict__ wemb, const float* __restrict__ pemb,
    const float* __restrict__ temb, const float* __restrict__ g, const float* __restrict__ be,
    float* __restrict__ x, u16* __restrict__ xb)
{
  const int t = blockIdx.x;
  const int s = t & 2047;
  const int id = ids[t];
  const int tid = threadIdx.x;
  const int wave = tid >> 6, lane = tid & 63;

  float vals[3]; float sum = 0.f, ssq = 0.f;
#pragma unroll
  for (int i = 0; i < 3; ++i) {
    const int d = tid + i * 256;
    const float v = wemb[(size_t)id * 768 + d] + pemb[(size_t)(s + 2) * 768 + d] + temb[d];
    vals[i] = v; sum += v; ssq += v * v;
  }
#pragma unroll
  for (int off = 32; off; off >>= 1) { sum += __shfl_xor(sum, off, 64); ssq += __shfl_xor(ssq, off, 64); }
  __shared__ float rb[8];
  if (lane == 0) { rb[wave] = sum; rb[4 + wave] = ssq; }
  __syncthreads();
  sum = rb[0] + rb[1] + rb[2] + rb[3];
  ssq = rb[4] + rb[5] + rb[6] + rb[7];
  const float mu = sum * (1.f / 768.f);
  const float var = ssq * (1.f / 768.f) - mu * mu;
  const float rstd = rsqrtf(var + 1e-5f);
#pragma unroll
  for (int i = 0; i < 3; ++i) {
    const int d = tid + i * 256;
    const float o = (vals[i] - mu) * rstd * g[d] + be[d];
    x[(size_t)t * 768 + d] = o;
    xb[(size_t)t * 768 + d] = f2bf(o);
  }
}

// ---------------------------------------------------------------------------
// Split-K reduce + bias + residual + LayerNorm. block per token.
// ---------------------------------------------------------------------------
template<int NC>
__global__ __launch_bounds__(256) void reduce_ln_kernel(
    const float* __restrict__ pb, const float* __restrict__ bias,
    const float* __restrict__ g, const float* __restrict__ be,
    float* x, u16* __restrict__ xb)
{
  const int t = blockIdx.x;
  const int tid = threadIdx.x;
  const int wave = tid >> 6, lane = tid & 63;

  float vals[3]; float sum = 0.f, ssq = 0.f;
#pragma unroll
  for (int i = 0; i < 3; ++i) {
    const int d = tid + i * 256;
    float v = x[(size_t)t * 768 + d] + bias[d];
#pragma unroll
    for (int c = 0; c < NC; ++c)
      v += pb[((size_t)c * 4096 + t) * 768 + d];
    vals[i] = v; sum += v; ssq += v * v;
  }
#pragma unroll
  for (int off = 32; off; off >>= 1) { sum += __shfl_xor(sum, off, 64); ssq += __shfl_xor(ssq, off, 64); }
  __shared__ float rb[8];
  if (lane == 0) { rb[wave] = sum; rb[4 + wave] = ssq; }
  __syncthreads();
  sum = rb[0] + rb[1] + rb[2] + rb[3];
  ssq = rb[4] + rb[5] + rb[6] + rb[7];
  const float mu = sum * (1.f / 768.f);
  const float var = ssq * (1.f / 768.f) - mu * mu;
  const float rstd = rsqrtf(var + 1e-5f);
#pragma unroll
  for (int i = 0; i < 3; ++i) {
    const int d = tid + i * 256;
    const float o = (vals[i] - mu) * rstd * g[d] + be[d];
    x[(size_t)t * 768 + d] = o;
    xb[(size_t)t * 768 + d] = f2bf(o);
  }
}

// ---------------------------------------------------------------------------
// Head: out[b] = dot(x[b,0,:], Wtop[0:768]) + fts[b]*Wtop[768] + btop
// ---------------------------------------------------------------------------
__global__ __launch_bounds__(256) void head_kernel(
    const float* __restrict__ x, const float* __restrict__ fts,
    const float* __restrict__ wtop, const float* __restrict__ btop, float* __restrict__ out)
{
  const int tid = threadIdx.x;
  const int wave = tid >> 6, lane = tid & 63;
  __shared__ float rb[4];
  for (int b = 0; b < 2; ++b) {
    float s = 0.f;
    for (int d = tid; d < 768; d += 256)
      s += x[(size_t)b * 2048 * 768 + d] * wtop[d];
#pragma unroll
    for (int off = 32; off; off >>= 1) s += __shfl_xor(s, off, 64);
    if (lane == 0) rb[wave] = s;
    __syncthreads();
    if (tid == 0) {
      float r = rb[0] + rb[1] + rb[2] + rb[3];
      r += fts[b] * wtop[768] + btop[0];
      out[b] = r;
    }
    __syncthreads();
  }
}

// ---------------------------------------------------------------------------
extern "C" void kernel_launch(void* const* d_in, const int* in_sizes, int n_in,
                              void* d_out, int out_size, void* d_ws, size_t ws_size,
                              hipStream_t stream)
{
  const int*   ids  = (const int*)d_in[0];
  const float* mask = (const float*)d_in[1];
  const float* fts  = (const float*)d_in[2];
  const float* wemb = (const float*)d_in[3];
  const float* pemb = (const float*)d_in[4];
  const float* temb = (const float*)d_in[5];
  const float* lneg = (const float*)d_in[6];
  const float* lneb = (const float*)d_in[7];
  const float* Wq   = (const float*)d_in[8];
  const float* bq   = (const float*)d_in[9];
  const float* Wk   = (const float*)d_in[10];
  const float* bk   = (const float*)d_in[11];
  const float* Wv   = (const float*)d_in[12];
  const float* bvv  = (const float*)d_in[13];
  const float* Wo   = (const float*)d_in[14];
  const float* bo   = (const float*)d_in[15];
  const float* ln1g = (const float*)d_in[16];
  const float* ln1b = (const float*)d_in[17];
  const float* W1   = (const float*)d_in[18];
  const float* b1   = (const float*)d_in[19];
  const float* W2   = (const float*)d_in[20];
  const float* b2   = (const float*)d_in[21];
  const float* ln2g = (const float*)d_in[22];
  const float* ln2b = (const float*)d_in[23];
  const float* wtop = (const float*)d_in[24];
  const float* btop = (const float*)d_in[25];

  const size_t SQ   = 768 * 768;
  const size_t SQ3  = 2304 * 768;
  const size_t SF   = 3072 * 768;
  const size_t perL = SQ3 + SQ + 2 * SF;
  const size_t NTOK = 4096;
  const size_t HDSZ = (size_t)2 * 12 * 2048 * 64;   // per q/k/vt buffer elems
  const size_t PAD  = 4096;                          // band-edge overread pad

  const size_t fixedBytes =
      NTOK * 768 * 4          // x
    + NTOK * 768 * 2          // xb
    + 4 * NTOK * 768 * 4      // pb (split-K partials)
    + NTOK * 768 * 2          // ab
    + NTOK * 3072 * 2         // hb
    + 3 * (HDSZ + PAD) * 2;   // qB,kB,vtB
  const bool batched = ws_size >= fixedBytes + 12 * perL * 2 + 65536;
  const size_t nw = batched ? 12 : 1;

  char* p = (char*)d_ws;
  u16* wTqkv = (u16*)p; p += nw * SQ3 * 2;
  u16* wTo   = (u16*)p; p += nw * SQ  * 2;
  u16* wT1   = (u16*)p; p += nw * SF  * 2;
  u16* wT2   = (u16*)p; p += nw * SF  * 2;
  float* x  = (float*)p; p += NTOK * 768 * 4;
  u16*   xb = (u16*)p;   p += NTOK * 768 * 2;
  float* pb = (float*)p; p += 4 * NTOK * 768 * 4;
  u16*   ab = (u16*)p;   p += NTOK * 768 * 2;
  u16*   hb = (u16*)p;   p += NTOK * 3072 * 2;
  u16*   qB  = (u16*)p;  p += (HDSZ + PAD) * 2;
  u16*   kB  = (u16*)p;  p += (HDSZ + PAD) * 2;
  u16*   vtB = (u16*)p;  p += (HDSZ + PAD) * 2;

  if (batched) {
    transpose_cvt<<<dim3(24, 24, 12), 256, 0, stream>>>(Wq, wTqkv,             768, 768,  SQ, SQ3);
    transpose_cvt<<<dim3(24, 24, 12), 256, 0, stream>>>(Wk, wTqkv + 768 * 768, 768, 768,  SQ, SQ3);
    transpose_cvt<<<dim3(24, 24, 12), 256, 0, stream>>>(Wv, wTqkv + 1536 * 768,768, 768,  SQ, SQ3);
    transpose_cvt<<<dim3(24, 24, 12), 256, 0, stream>>>(Wo, wTo, 768, 768,  SQ, SQ);
    transpose_cvt<<<dim3(96, 24, 12), 256, 0, stream>>>(W1, wT1, 768, 3072, SF, SF);
    transpose_cvt<<<dim3(24, 96, 12), 256, 0, stream>>>(W2, wT2, 3072, 768, SF, SF);
  }

  embed_ln_kernel<<<4096, 256, 0, stream>>>(ids, wemb, pemb, temb, lneg, lneb, x, xb);

  for (int i = 0; i < 12; ++i) {
    const u16 *WqkvTl, *WoTl, *W1Tl, *W2Tl;
    if (batched) {
      WqkvTl = wTqkv + (size_t)i * SQ3; WoTl = wTo + (size_t)i * SQ;
      W1Tl = wT1 + (size_t)i * SF;      W2Tl = wT2 + (size_t)i * SF;
    } else {
      transpose_cvt<<<dim3(24, 24, 1), 256, 0, stream>>>(Wq + (size_t)i * SQ, wTqkv,             768, 768, SQ, SQ3);
      transpose_cvt<<<dim3(24, 24, 1), 256, 0, stream>>>(Wk + (size_t)i * SQ, wTqkv + 768 * 768, 768, 768, SQ, SQ3);
      transpose_cvt<<<dim3(24, 24, 1), 256, 0, stream>>>(Wv + (size_t)i * SQ, wTqkv + 1536 * 768,768, 768, SQ, SQ3);
      transpose_cvt<<<dim3(24, 24, 1), 256, 0, stream>>>(Wo + (size_t)i * SQ, wTo, 768, 768, SQ, SQ);
      transpose_cvt<<<dim3(96, 24, 1), 256, 0, stream>>>(W1 + (size_t)i * SF, wT1, 768, 3072, SF, SF);
      transpose_cvt<<<dim3(24, 96, 1), 256, 0, stream>>>(W2 + (size_t)i * SF, wT2, 3072, 768, SF, SF);
      WqkvTl = wTqkv; WoTl = wTo; W1Tl = wT1; W2Tl = wT2;
    }

    // fused QKV projection: [4096,768] @ [768,2304] -> q,k,[B,H,S,64]; vt [B,H,64,S]
    gemm_bt<3><<<dim3(18, 32), 256, 0, stream>>>(
        xb, WqkvTl, bq + (size_t)i * 768, bk + (size_t)i * 768, bvv + (size_t)i * 768,
        nullptr, nullptr, qB, kB, vtB, 4096, 2304, 768, 768);

    attn_mfma<<<dim3(32, 12, 2), 256, 0, stream>>>(qB, kB, vtB, mask, ab, g_halves[i]);

    // out-proj: split-K=2 -> partials, then reduce+residual+LN
    gemm_bt<4><<<dim3(6, 32, 2), 256, 0, stream>>>(
        ab, WoTl, nullptr, nullptr, nullptr, pb, nullptr,
        nullptr, nullptr, nullptr, 4096, 768, 768, 384);
    reduce_ln_kernel<2><<<4096, 256, 0, stream>>>(
        pb, bo + (size_t)i * 768, ln1g + (size_t)i * 768, ln1b + (size_t)i * 768, x, xb);

    // FFN1: 256x256 8-phase GEMM v2, gelu epilogue
    gemm8p<2><<<dim3(12, 16), 512, 0, stream>>>(
        xb, W1Tl, b1 + (size_t)i * 3072, nullptr, hb, 4096, 3072, 768, 768);

    // FFN2: 256x256 8-phase GEMM v2, split-K=4 -> partials, then reduce+residual+LN
    gemm8p<4><<<dim3(3, 16, 4), 512, 0, stream>>>(
        hb, W2Tl, nullptr, pb, nullptr, 4096, 768, 3072, 768);
    reduce_ln_kernel<4><<<4096, 256, 0, stream>>>(
        pb, b2 + (size_t)i * 768, ln2g + (size_t)i * 768, ln2b + (size_t)i * 768, x, xb);
  }

  head_kernel<<<1, 256, 0, stream>>>(x, fts, wtop, btop, (float*)d_out);
}